// Round 2
// baseline (265.642 us; speedup 1.0000x reference)
//
#include <hip/hip_runtime.h>
#include <math.h>

constexpr int BN = 8192;
constexpr int KN = 4;
constexpr int MN = 6;
constexpr int XD = 2 * KN;   // 8 features per mode
constexpr int XS = MN * XD;  // 48 floats per row of fourier_embed

// exp(-T*d2) with T=2  ->  exp2(d2 * (-2*log2(e)))
constexpr float C_EXP = -2.8853900817779268f;

__global__ __launch_bounds__(256) void pair_sums(const float* __restrict__ x,
                                                 float* __restrict__ S) {
    const int tid = threadIdx.x;
    const int lane = tid & 63;
    // wave index: force uniform so the j-loop addresses are provably scalar
    const int slice = __builtin_amdgcn_readfirstlane(tid >> 6);

    const int b = blockIdx.x;
    const int rb = b & 127;   // 128 row-blocks of 64 rows
    const int n = b >> 7;     // mode

    const int i = rb * 64 + lane;
    const float* xi = x + (size_t)i * XS + n * XD;
    const float x0 = xi[0], x1 = xi[1], x2 = xi[2], x3 = xi[3];
    const float x4 = xi[4], x5 = xi[5], x6 = xi[6], x7 = xi[7];

    const int j0 = slice * (BN / 4);
    const int j1 = j0 + (BN / 4);
    const float* xb = x + n * XD;

    float s = 0.0f;
#pragma unroll 4
    for (int j = j0; j < j1; ++j) {
        const float* xj = xb + (size_t)j * XS;
        float d, d2;
        d = x0 - xj[0]; d2 = d * d;
        d = x1 - xj[1]; d2 = fmaf(d, d, d2);
        d = x2 - xj[2]; d2 = fmaf(d, d, d2);
        d = x3 - xj[3]; d2 = fmaf(d, d, d2);
        d = x4 - xj[4]; d2 = fmaf(d, d, d2);
        d = x5 - xj[5]; d2 = fmaf(d, d, d2);
        d = x6 - xj[6]; d2 = fmaf(d, d, d2);
        d = x7 - xj[7]; d2 = fmaf(d, d, d2);
        s += __builtin_amdgcn_exp2f(d2 * C_EXP);
    }
    // diagonal term (j==i) contributed exactly exp2(-0.0f)==1.0f; remove it
    if (i >= j0 && i < j1) s -= 1.0f;

    __shared__ float lds[256];
    lds[tid] = s;
    __syncthreads();
    if (tid < 64) {
        float tot = lds[tid] + lds[tid + 64] + lds[tid + 128] + lds[tid + 192];
        S[n * BN + rb * 64 + tid] = tot;
    }
}

__global__ __launch_bounds__(1024) void finalize(const float* __restrict__ S,
                                                 const float* __restrict__ ang,
                                                 float* __restrict__ out) {
    const int tid = threadIdx.x;
    const int NT = 1024;
    __shared__ float lds[1024];

    auto reduce = [&](float v) -> float {
        lds[tid] = v;
        __syncthreads();
        for (int off = NT / 2; off > 0; off >>= 1) {
            if (tid < off) lds[tid] += lds[tid + off];
            __syncthreads();
        }
        float r = lds[0];
        __syncthreads();
        return r;
    };

    // ---- Phase A: circular mean of each angle column ----
    float ss[KN] = {0, 0, 0, 0}, sc[KN] = {0, 0, 0, 0};
    for (int i = tid; i < BN; i += NT) {
#pragma unroll
        for (int k = 0; k < KN; ++k) {
            float a = ang[i * KN + k];
            ss[k] += sinf(a);
            sc[k] += cosf(a);
        }
    }
    float mu[KN];
#pragma unroll
    for (int k = 0; k < KN; ++k) {
        float tss = reduce(ss[k]);
        float tsc = reduce(sc[k]);
        mu[k] = atan2f(tss, tsc);  // positive common scale cancels in atan2
    }

    // ---- Phase B: covariance of sin residuals, corr^2 spread ----
    float cv[10];
#pragma unroll
    for (int c = 0; c < 10; ++c) cv[c] = 0.0f;
    for (int i = tid; i < BN; i += NT) {
        float sv[KN];
#pragma unroll
        for (int k = 0; k < KN; ++k) sv[k] = sinf(ang[i * KN + k] - mu[k]);
        int c = 0;
#pragma unroll
        for (int k = 0; k < KN; ++k)
#pragma unroll
            for (int l = k; l < KN; ++l)
                cv[c++] += sv[k] * sv[l];
    }
    float cov[10];
    for (int c = 0; c < 10; ++c) cov[c] = reduce(cv[c]) * (1.0f / (float)BN);
    // layout (k<=l): 00,01,02,03,11,12,13,22,23,33
    const float var0 = cov[0], var1 = cov[4], var2 = cov[7], var3 = cov[9];
    float spread = 0.0f;
    {
        const float vk[6] = {var0, var0, var0, var1, var1, var2};
        const float vl[6] = {var1, var2, var3, var2, var3, var3};
        const int ic[6] = {1, 2, 3, 5, 6, 8};
#pragma unroll
        for (int p = 0; p < 6; ++p) {
            float den = sqrtf(vk[p] * vl[p] + 1e-8f);
            float cr = cov[ic[p]] / den;
            spread += cr * cr;
        }
        spread *= (1.0f / 6.0f);
    }

    // ---- Phase C: per-mode mean of log(S) ----
    const float logBm1 = logf((float)(BN - 1));
    const float w[6] = {0.0f, 0.19615242270663188f, 0.4641016151377544f,
                        0.7320508075688773f, 0.9282032302755088f, 1.0f};
    float unif[MN];
    float total_unif = 0.0f;
    for (int nn = 0; nn < MN; ++nn) {
        float ls = 0.0f;
        for (int i = tid; i < BN; i += NT) ls += logf(S[nn * BN + i]);
        float t = reduce(ls);
        unif[nn] = t * (1.0f / (float)BN) - logBm1;
        total_unif += w[nn] * unif[nn];
    }

    if (tid == 0) {
        out[0] = total_unif;
        out[1] = spread;
        out[2] = total_unif + spread;  // SPREAD_W = 1.0
#pragma unroll
        for (int nn = 0; nn < MN; ++nn) out[3 + nn] = unif[nn];
    }
}

extern "C" void kernel_launch(void* const* d_in, const int* in_sizes, int n_in,
                              void* d_out, int out_size, void* d_ws, size_t ws_size,
                              hipStream_t stream) {
    const float* angles = (const float*)d_in[0];        // (8192, 4) f32
    const float* fourier = (const float*)d_in[1];       // (8192, 48) f32
    float* out = (float*)d_out;                         // 9 floats
    float* S = (float*)d_ws;                            // 6*8192 f32 row sums

    pair_sums<<<dim3(MN * 128), dim3(256), 0, stream>>>(fourier, S);
    finalize<<<dim3(1), dim3(1024), 0, stream>>>(S, angles, out);
}

// Round 3
// 114.140 us; speedup vs baseline: 2.3273x; 2.3273x over previous
//
#include <hip/hip_runtime.h>
#include <math.h>

constexpr int BN = 8192;
constexpr int MN = 6;

// E = -T*log2(e)*d2 with T=2:  E = 2TL*g - TL*sq_i - TL*sq_j,  L=log2(e)
constexpr float TL    = 2.8853900817779268f;   // 2*log2(e)
constexpr float SCL_Z = 2.4022448795936154f;   // sqrt(2*T*L) = sqrt(5.77078016...)

typedef __bf16 bf16_t;
typedef bf16_t bf16x8 __attribute__((ext_vector_type(8)));
typedef float f32x4 __attribute__((ext_vector_type(4)));

union PK { bf16_t h[8]; uint4 u; };

__device__ __forceinline__ bf16x8 frag_of(uint4 u) {
    return __builtin_bit_cast(bf16x8, u);
}

// ---------------------------------------------------------------------------
// K0: pack MFMA fragments.  One thread per (mode n, row j).
// A-frag octets (k-octet o = lane>>4):  o0=zh  o1=zl  o2=zh  o3=[1,1,sh,sl,0..]
// B-frag octets:                        o0=zh  o1=zh  o2=zl  o3=[sh,sl,1,1,0..]
// => sum_k A_ik B_jk = zh_i*zh_j + zl_i*zh_j + zh_i*zl_j + sh_j+sl_j+sh_i+sl_i
//                    ~ 2TL*g_ij - TL*sq_i - TL*sq_j = E_ij     (err ~ 2^-18)
// ---------------------------------------------------------------------------
__global__ __launch_bounds__(256) void prep(const float* __restrict__ x,
                                            uint4* __restrict__ Ap,
                                            uint4* __restrict__ Bp) {
    int idx = blockIdx.x * 256 + threadIdx.x;
    if (idx >= MN * BN) return;
    int n = idx >> 13;
    int j = idx & (BN - 1);
    const float* p = x + (size_t)j * 48 + n * 8;

    PK zh, zl, a3, b3;
    float sq = 0.f;
#pragma unroll
    for (int k = 0; k < 8; ++k) {
        float v = p[k];
        sq = fmaf(v, v, sq);
        float z = SCL_Z * v;
        bf16_t h = (bf16_t)z;
        zh.h[k] = h;
        zl.h[k] = (bf16_t)(z - (float)h);
    }
    float s = -TL * sq;
    bf16_t sh = (bf16_t)s;
    bf16_t sl = (bf16_t)(s - (float)sh);
    bf16_t one = (bf16_t)1.0f, zero = (bf16_t)0.0f;
    a3.h[0] = one; a3.h[1] = one; a3.h[2] = sh;  a3.h[3] = sl;
    b3.h[0] = sh;  b3.h[1] = sl;  b3.h[2] = one; b3.h[3] = one;
#pragma unroll
    for (int k = 4; k < 8; ++k) { a3.h[k] = zero; b3.h[k] = zero; }

    size_t base = ((size_t)(n * 512 + (j >> 4))) * 64 + (j & 15);
    Ap[base +  0] = zh.u;
    Ap[base + 16] = zl.u;
    Ap[base + 32] = zh.u;
    Ap[base + 48] = a3.u;
    Bp[base +  0] = zh.u;
    Bp[base + 16] = zh.u;
    Bp[base + 32] = zl.u;
    Bp[base + 48] = b3.u;
}

// ---------------------------------------------------------------------------
// K1: pairwise kernel.  Block = (mode n, 64-row group).  4 waves split j.
// Wave: 4 A-frags (4 row-tiles of 16), sweeps 128 col-tiles of 16.
// Per tile: 1 B-load, 4 mfma (E directly), 16 exp2, 16 adds.
// Tail: row-sums -> log -> per-block partial sum of log -> lp[block].
// ---------------------------------------------------------------------------
__global__ __launch_bounds__(256) void pair_mfma(const uint4* __restrict__ Ap,
                                                 const uint4* __restrict__ Bp,
                                                 float* __restrict__ lp) {
    const int tid  = threadIdx.x;
    const int lane = tid & 63;
    const int w    = tid >> 6;
    const int b    = blockIdx.x;
    const int n    = b >> 7;          // mode
    const int rb   = b & 127;         // 64-row group
    const int rb4  = rb * 4;          // first 16-row tile index

    bf16x8 af[4];
#pragma unroll
    for (int t = 0; t < 4; ++t)
        af[t] = frag_of(Ap[((size_t)(n * 512 + rb4 + t)) * 64 + lane]);

    float racc[16];
#pragma unroll
    for (int q = 0; q < 16; ++q) racc[q] = 0.f;

    const int dd = (lane & 15) - 4 * (lane >> 4);  // diag when dd == reg
    const uint4* bbase = Bp + ((size_t)n * 512) * 64 + lane;
    const f32x4 z4 = {0.f, 0.f, 0.f, 0.f};

    const int jt0 = w * 128, jt1 = jt0 + 128;
    uint4 braw = bbase[(size_t)jt0 * 64];
    for (int jt = jt0; jt < jt1; ++jt) {
        bf16x8 bf = frag_of(braw);
        if (jt + 1 < jt1) braw = bbase[(size_t)(jt + 1) * 64];

        f32x4 d[4];
#pragma unroll
        for (int t = 0; t < 4; ++t)
            d[t] = __builtin_amdgcn_mfma_f32_16x16x32_bf16(af[t], bf, z4, 0, 0, 0);

#pragma unroll
        for (int t = 0; t < 4; ++t) {
            if (jt == rb4 + t) {  // wave-uniform: diagonal tile
#pragma unroll
                for (int r = 0; r < 4; ++r) {
                    float tv = __builtin_amdgcn_exp2f(d[t][r]);
                    racc[t * 4 + r] += (dd == r) ? 0.f : tv;
                }
            } else {
#pragma unroll
                for (int r = 0; r < 4; ++r)
                    racc[t * 4 + r] += __builtin_amdgcn_exp2f(d[t][r]);
            }
        }
    }

    // reduce each racc over the 16 lanes of its row-group (low 4 lane bits)
#pragma unroll
    for (int q = 0; q < 16; ++q) {
        float v = racc[q];
        v += __shfl_xor(v, 1);
        v += __shfl_xor(v, 2);
        v += __shfl_xor(v, 4);
        v += __shfl_xor(v, 8);
        racc[q] = v;
    }

    __shared__ float smem[4][64];
    if ((lane & 15) == 0) {
        int g = lane >> 4;
#pragma unroll
        for (int t = 0; t < 4; ++t)
#pragma unroll
            for (int r = 0; r < 4; ++r)
                smem[w][t * 16 + g * 4 + r] = racc[t * 4 + r];
    }
    __syncthreads();

    if (tid < 64) {
        float s = smem[0][tid] + smem[1][tid] + smem[2][tid] + smem[3][tid];
        float lg = logf(s);
        lg += __shfl_xor(lg, 1);
        lg += __shfl_xor(lg, 2);
        lg += __shfl_xor(lg, 4);
        lg += __shfl_xor(lg, 8);
        lg += __shfl_xor(lg, 16);
        lg += __shfl_xor(lg, 32);
        if (tid == 0) lp[b] = lg;
    }
}

// ---------------------------------------------------------------------------
// F1: per-block partial sums of sin/cos of each angle column. 32 blocks x 256.
// ---------------------------------------------------------------------------
__global__ __launch_bounds__(256) void ang_part(const float* __restrict__ ang,
                                                float* __restrict__ outp) {
    const int tid = threadIdx.x;
    const int i = blockIdx.x * 256 + tid;  // exactly 8192 threads
    float ss[4], sc[4];
#pragma unroll
    for (int k = 0; k < 4; ++k) {
        float s, c;
        __sincosf(ang[i * 4 + k], &s, &c);
        ss[k] = s; sc[k] = c;
    }
    __shared__ float red[256];
#pragma unroll
    for (int q = 0; q < 8; ++q) {
        red[tid] = (q < 4) ? ss[q] : sc[q - 4];
        __syncthreads();
        for (int off = 128; off > 0; off >>= 1) {
            if (tid < off) red[tid] += red[tid + off];
            __syncthreads();
        }
        if (tid == 0) outp[blockIdx.x * 8 + q] = red[0];
        __syncthreads();
    }
}

// ---------------------------------------------------------------------------
// F2: final assembly — mu, covariance/spread, per-mode unif, outputs.
// ---------------------------------------------------------------------------
__global__ __launch_bounds__(1024) void final_asm(const float* __restrict__ ang,
                                                  const float* __restrict__ angp,
                                                  const float* __restrict__ lp,
                                                  float* __restrict__ out) {
    const int tid = threadIdx.x;
    __shared__ float lds[1024];
    __shared__ float mu_s[4];

    auto reduce = [&](float v) -> float {
        lds[tid] = v;
        __syncthreads();
        for (int off = 512; off > 0; off >>= 1) {
            if (tid < off) lds[tid] += lds[tid + off];
            __syncthreads();
        }
        float r = lds[0];
        __syncthreads();
        return r;
    };

    if (tid < 8) {
        float s = 0.f;
        for (int bk = 0; bk < 32; ++bk) s += angp[bk * 8 + tid];
        lds[tid] = s;
    }
    __syncthreads();
    if (tid < 4) mu_s[tid] = atan2f(lds[tid], lds[4 + tid]);
    __syncthreads();
    float mu[4];
#pragma unroll
    for (int k = 0; k < 4; ++k) mu[k] = mu_s[k];
    __syncthreads();

    float cv[10];
#pragma unroll
    for (int c = 0; c < 10; ++c) cv[c] = 0.f;
    for (int i = tid; i < BN; i += 1024) {
        float sv[4];
#pragma unroll
        for (int k = 0; k < 4; ++k) sv[k] = sinf(ang[i * 4 + k] - mu[k]);
        int c = 0;
#pragma unroll
        for (int k = 0; k < 4; ++k)
#pragma unroll
            for (int l = k; l < 4; ++l)
                cv[c++] += sv[k] * sv[l];
    }
    float cov[10];
    for (int c = 0; c < 10; ++c) cov[c] = reduce(cv[c]) * (1.0f / (float)BN);

    float spread = 0.f;
    {
        const float v0 = cov[0], v1 = cov[4], v2 = cov[7], v3 = cov[9];
        const float vk[6] = {v0, v0, v0, v1, v1, v2};
        const float vl[6] = {v1, v2, v3, v2, v3, v3};
        const int ic[6] = {1, 2, 3, 5, 6, 8};
#pragma unroll
        for (int p = 0; p < 6; ++p) {
            float den = sqrtf(vk[p] * vl[p] + 1e-8f);
            float cr = cov[ic[p]] / den;
            spread += cr * cr;
        }
        spread *= (1.0f / 6.0f);
    }

    // per-mode sums of log-partials: lp[768], 128 per mode
    lds[tid] = (tid < 768) ? lp[tid] : 0.f;
    __syncthreads();
    for (int off = 64; off > 0; off >>= 1) {
        if ((tid & 127) < off && tid < 768) lds[tid] += lds[tid + off];
        __syncthreads();
    }

    if (tid == 0) {
        const float wgt[6] = {0.0f, 0.19615242270663188f, 0.4641016151377544f,
                              0.7320508075688773f, 0.9282032302755088f, 1.0f};
        const float logBm1 = logf((float)(BN - 1));
        float total_unif = 0.f, unif[6];
#pragma unroll
        for (int m = 0; m < 6; ++m) {
            unif[m] = lds[m * 128] * (1.0f / (float)BN) - logBm1;
            total_unif += wgt[m] * unif[m];
        }
        out[0] = total_unif;
        out[1] = spread;
        out[2] = total_unif + spread;
#pragma unroll
        for (int m = 0; m < 6; ++m) out[3 + m] = unif[m];
    }
}

extern "C" void kernel_launch(void* const* d_in, const int* in_sizes, int n_in,
                              void* d_out, int out_size, void* d_ws, size_t ws_size,
                              hipStream_t stream) {
    const float* angles  = (const float*)d_in[0];   // (8192, 4) f32
    const float* fourier = (const float*)d_in[1];   // (8192, 48) f32
    float* out = (float*)d_out;                     // 9 floats

    char* ws = (char*)d_ws;
    uint4* Bp   = (uint4*)(ws + 0);                 // 3,145,728 B
    uint4* Ap   = (uint4*)(ws + 3145728);           // 3,145,728 B
    float* lp   = (float*)(ws + 6291456);           // 768 f32
    float* angp = (float*)(ws + 6294528);           // 256 f32

    prep<<<dim3(192), dim3(256), 0, stream>>>(fourier, Ap, Bp);
    pair_mfma<<<dim3(MN * 128), dim3(256), 0, stream>>>(Ap, Bp, lp);
    ang_part<<<dim3(32), dim3(256), 0, stream>>>(angles, angp);
    final_asm<<<dim3(1), dim3(1024), 0, stream>>>(angles, angp, lp, out);
}

// Round 4
// 60.367 us; speedup vs baseline: 4.4004x; 1.8908x over previous
//
#include <hip/hip_runtime.h>
#include <math.h>

constexpr int BN = 8192;
constexpr int MN = 6;

// E = -T*log2(e)*d2 with T=2:  E = 2TL*g - TL*sq_i - TL*sq_j,  L=log2(e)
constexpr float TL    = 2.8853900817779268f;   // 2*log2(e)
constexpr float SCL_Z = 2.4022448795936154f;   // sqrt(2*T*L)

typedef __bf16 bf16_t;
typedef bf16_t bf16x8 __attribute__((ext_vector_type(8)));
typedef float f32x4 __attribute__((ext_vector_type(4)));

union PK { bf16_t h[8]; uint4 u; };

__device__ __forceinline__ bf16x8 frag_of(uint4 u) {
    return __builtin_bit_cast(bf16x8, u);
}

__device__ __host__ __forceinline__ int midx(int a, int b) {
    // index into upper-triangle (a<=b) of 8x8, row-major packed
    return 8 * a - (a * (a - 1)) / 2 + (b - a);
}

// ---------------------------------------------------------------------------
// K0: blocks 0..191  -> pack MFMA fragments (one thread per (mode, row)).
//     blocks 192..223 -> angle second moments (36 pair moments + 8 sums).
// Fragment math: sum_k A_ik B_jk ~ 2TL*g_ij - TL*sq_i - TL*sq_j = E_ij,
// hi/lo bf16 split gives ~2^-18 rel err; MFMA output IS the exp2 exponent.
// ---------------------------------------------------------------------------
__global__ __launch_bounds__(256) void prep_ang(const float* __restrict__ x,
                                                const float* __restrict__ ang,
                                                uint4* __restrict__ Ap,
                                                uint4* __restrict__ Bp,
                                                float* __restrict__ angp) {
    const int blk = blockIdx.x;
    const int tid = threadIdx.x;
    if (blk < 192) {
        int idx = blk * 256 + tid;
        int n = idx >> 13;
        int j = idx & (BN - 1);
        const float* p = x + (size_t)j * 48 + n * 8;

        PK zh, zl, a3, b3;
        float sq = 0.f;
#pragma unroll
        for (int k = 0; k < 8; ++k) {
            float v = p[k];
            sq = fmaf(v, v, sq);
            float z = SCL_Z * v;
            bf16_t h = (bf16_t)z;
            zh.h[k] = h;
            zl.h[k] = (bf16_t)(z - (float)h);
        }
        float s = -TL * sq;
        bf16_t sh = (bf16_t)s;
        bf16_t sl = (bf16_t)(s - (float)sh);
        bf16_t one = (bf16_t)1.0f, zero = (bf16_t)0.0f;
        a3.h[0] = one; a3.h[1] = one; a3.h[2] = sh;  a3.h[3] = sl;
        b3.h[0] = sh;  b3.h[1] = sl;  b3.h[2] = one; b3.h[3] = one;
#pragma unroll
        for (int k = 4; k < 8; ++k) { a3.h[k] = zero; b3.h[k] = zero; }

        size_t base = ((size_t)(n * 512 + (j >> 4))) * 64 + (j & 15);
        Ap[base +  0] = zh.u;
        Ap[base + 16] = zl.u;
        Ap[base + 32] = zh.u;
        Ap[base + 48] = a3.u;
        Bp[base +  0] = zh.u;
        Bp[base + 16] = zh.u;
        Bp[base + 32] = zl.u;
        Bp[base + 48] = b3.u;
    } else {
        const int i = (blk - 192) * 256 + tid;  // 32 blocks cover 8192 rows
        float v[8];
#pragma unroll
        for (int k = 0; k < 4; ++k) __sincosf(ang[i * 4 + k], &v[k], &v[4 + k]);
        float acc[44];
        int c = 0;
#pragma unroll
        for (int a = 0; a < 8; ++a)
#pragma unroll
            for (int bq = a; bq < 8; ++bq) acc[c++] = v[a] * v[bq];
#pragma unroll
        for (int a = 0; a < 8; ++a) acc[36 + a] = v[a];

#pragma unroll
        for (int q = 0; q < 44; ++q) {
            float s = acc[q];
            s += __shfl_xor(s, 1);  s += __shfl_xor(s, 2);
            s += __shfl_xor(s, 4);  s += __shfl_xor(s, 8);
            s += __shfl_xor(s, 16); s += __shfl_xor(s, 32);
            acc[q] = s;
        }
        __shared__ float sm[4][44];
        const int w = tid >> 6, lane = tid & 63;
        if (lane == 0)
#pragma unroll
            for (int q = 0; q < 44; ++q) sm[w][q] = acc[q];
        __syncthreads();
        if (tid < 44)
            angp[(blk - 192) * 44 + tid] =
                sm[0][tid] + sm[1][tid] + sm[2][tid] + sm[3][tid];
    }
}

// ---------------------------------------------------------------------------
// K1: pairwise kernel.  Block = (mode, 64-row group), 8 waves split j-range.
// Inner loop is branch-free: {load, 8 mfma, 32 exp2, 32 add} per 2 tiles.
// Diagonal handled post-loop by the single wave owning those 4 tiles.
// ---------------------------------------------------------------------------
__global__ __launch_bounds__(512, 6) void pair_mfma(const uint4* __restrict__ Ap,
                                                    const uint4* __restrict__ Bp,
                                                    float* __restrict__ lp) {
    const int tid  = threadIdx.x;
    const int lane = tid & 63;
    const int w    = __builtin_amdgcn_readfirstlane(tid >> 6);
    const int b    = blockIdx.x;
    const int n    = b >> 7;          // mode
    const int rb   = b & 127;         // 64-row group
    const int rb4  = rb * 4;          // first 16-row tile index

    bf16x8 af[4];
#pragma unroll
    for (int t = 0; t < 4; ++t)
        af[t] = frag_of(Ap[((size_t)(n * 512 + rb4 + t)) * 64 + lane]);

    float racc[16];
#pragma unroll
    for (int q = 0; q < 16; ++q) racc[q] = 0.f;

    const uint4* bbase = Bp + ((size_t)n * 512) * 64 + lane;
    const f32x4 z4 = {0.f, 0.f, 0.f, 0.f};

    const int jt0 = w * 64, jt1 = jt0 + 64;
    uint4 b0 = bbase[(size_t)jt0 * 64];
    uint4 b1 = bbase[(size_t)(jt0 + 1) * 64];
    for (int jt = jt0; jt < jt1; jt += 2) {
        // prefetch depth-2; final-iter over-read (<=2 tiles) lands in Ap: harmless
        uint4 p0 = bbase[(size_t)(jt + 2) * 64];
        uint4 p1 = bbase[(size_t)(jt + 3) * 64];

        f32x4 d[4];
        bf16x8 bf = frag_of(b0);
#pragma unroll
        for (int t = 0; t < 4; ++t)
            d[t] = __builtin_amdgcn_mfma_f32_16x16x32_bf16(af[t], bf, z4, 0, 0, 0);
#pragma unroll
        for (int t = 0; t < 4; ++t)
#pragma unroll
            for (int r = 0; r < 4; ++r)
                racc[t * 4 + r] += __builtin_amdgcn_exp2f(d[t][r]);

        bf = frag_of(b1);
#pragma unroll
        for (int t = 0; t < 4; ++t)
            d[t] = __builtin_amdgcn_mfma_f32_16x16x32_bf16(af[t], bf, z4, 0, 0, 0);
#pragma unroll
        for (int t = 0; t < 4; ++t)
#pragma unroll
            for (int r = 0; r < 4; ++r)
                racc[t * 4 + r] += __builtin_amdgcn_exp2f(d[t][r]);

        b0 = p0; b1 = p1;
    }

    // diagonal fix-up: the wave whose j-range holds tiles rb4..rb4+3 subtracts
    // the diagonal elements (row==col within tile t: reg r == dd)
    if ((rb4 >> 6) == w) {
        const int dd = (lane & 15) - 4 * (lane >> 4);
#pragma unroll
        for (int t = 0; t < 4; ++t) {
            bf16x8 bf = frag_of(bbase[(size_t)(rb4 + t) * 64]);
            f32x4 d = __builtin_amdgcn_mfma_f32_16x16x32_bf16(af[t], bf, z4, 0, 0, 0);
#pragma unroll
            for (int r = 0; r < 4; ++r)
                if (dd == r) racc[t * 4 + r] -= __builtin_amdgcn_exp2f(d[r]);
        }
    }

    // reduce each racc over the 16 lanes of its column group (low 4 lane bits)
#pragma unroll
    for (int q = 0; q < 16; ++q) {
        float v = racc[q];
        v += __shfl_xor(v, 1);
        v += __shfl_xor(v, 2);
        v += __shfl_xor(v, 4);
        v += __shfl_xor(v, 8);
        racc[q] = v;
    }

    __shared__ float smem[8][64];
    if ((lane & 15) == 0) {
        int g = lane >> 4;
#pragma unroll
        for (int t = 0; t < 4; ++t)
#pragma unroll
            for (int r = 0; r < 4; ++r)
                smem[w][t * 16 + g * 4 + r] = racc[t * 4 + r];
    }
    __syncthreads();

    if (tid < 64) {
        float s = 0.f;
#pragma unroll
        for (int ww = 0; ww < 8; ++ww) s += smem[ww][tid];
        float lg = logf(s);
        lg += __shfl_xor(lg, 1);
        lg += __shfl_xor(lg, 2);
        lg += __shfl_xor(lg, 4);
        lg += __shfl_xor(lg, 8);
        lg += __shfl_xor(lg, 16);
        lg += __shfl_xor(lg, 32);
        if (tid == 0) lp[b] = lg;
    }
}

// ---------------------------------------------------------------------------
// K2: final assembly — mu/cov/spread from moments, per-mode unif, outputs.
// ---------------------------------------------------------------------------
__global__ __launch_bounds__(1024) void final_asm(const float* __restrict__ angp,
                                                  const float* __restrict__ lp,
                                                  float* __restrict__ out) {
    const int tid = threadIdx.x;
    __shared__ float mom[44];
    __shared__ float lds[1024];
    __shared__ float spread_s;

    if (tid < 44) {
        float s = 0.f;
        for (int bk = 0; bk < 32; ++bk) s += angp[bk * 44 + tid];
        mom[tid] = s;
    }
    __syncthreads();

    if (tid == 0) {
        float sm[4], cm[4];
#pragma unroll
        for (int k = 0; k < 4; ++k) {
            float S = mom[36 + k], C = mom[40 + k];
            float hyp = sqrtf(S * S + C * C);
            sm[k] = S / hyp;       // sin(mu_k)
            cm[k] = C / hyp;       // cos(mu_k)
        }
        auto COV = [&](int k, int l) -> float {
            int ks = k < l ? k : l, kl = k < l ? l : k;
            float mss = mom[midx(ks, kl)];
            float msc_kl = mom[midx(k, l + 4)];
            float msc_lk = mom[midx(l, k + 4)];
            float mcc = mom[midx(ks + 4, kl + 4)];
            return (cm[k] * cm[l] * mss - cm[k] * sm[l] * msc_kl -
                    sm[k] * cm[l] * msc_lk + sm[k] * sm[l] * mcc) *
                   (1.0f / (float)BN);
        };
        float var[4] = {COV(0, 0), COV(1, 1), COV(2, 2), COV(3, 3)};
        float spread = 0.f;
        const int pk[6] = {0, 0, 0, 1, 1, 2};
        const int pl[6] = {1, 2, 3, 2, 3, 3};
#pragma unroll
        for (int p = 0; p < 6; ++p) {
            float cv = COV(pk[p], pl[p]);
            float den = sqrtf(var[pk[p]] * var[pl[p]] + 1e-8f);
            float cr = cv / den;
            spread += cr * cr;
        }
        spread_s = spread * (1.0f / 6.0f);
    }

    // per-mode sums of log-partials: lp[768], 128 per mode
    lds[tid] = (tid < 768) ? lp[tid] : 0.f;
    __syncthreads();
    for (int off = 64; off > 0; off >>= 1) {
        if ((tid & 127) < off && tid < 768) lds[tid] += lds[tid + off];
        __syncthreads();
    }

    if (tid == 0) {
        const float wgt[6] = {0.0f, 0.19615242270663188f, 0.4641016151377544f,
                              0.7320508075688773f, 0.9282032302755088f, 1.0f};
        const float logBm1 = logf((float)(BN - 1));
        float total_unif = 0.f, unif[6];
#pragma unroll
        for (int m = 0; m < 6; ++m) {
            unif[m] = lds[m * 128] * (1.0f / (float)BN) - logBm1;
            total_unif += wgt[m] * unif[m];
        }
        out[0] = total_unif;
        out[1] = spread_s;
        out[2] = total_unif + spread_s;
#pragma unroll
        for (int m = 0; m < 6; ++m) out[3 + m] = unif[m];
    }
}

extern "C" void kernel_launch(void* const* d_in, const int* in_sizes, int n_in,
                              void* d_out, int out_size, void* d_ws, size_t ws_size,
                              hipStream_t stream) {
    const float* angles  = (const float*)d_in[0];   // (8192, 4) f32
    const float* fourier = (const float*)d_in[1];   // (8192, 48) f32
    float* out = (float*)d_out;                     // 9 floats

    char* ws = (char*)d_ws;
    uint4* Bp   = (uint4*)(ws + 0);                 // 3,145,728 B
    uint4* Ap   = (uint4*)(ws + 3145728);           // 3,145,728 B (also absorbs tail over-read)
    float* lp   = (float*)(ws + 6291456);           // 768 f32
    float* angp = (float*)(ws + 6294528);           // 32*44 f32

    prep_ang<<<dim3(224), dim3(256), 0, stream>>>(fourier, angles, Ap, Bp, angp);
    pair_mfma<<<dim3(MN * 128), dim3(512), 0, stream>>>(Ap, Bp, lp);
    final_asm<<<dim3(1), dim3(1024), 0, stream>>>(angp, lp, out);
}